// Round 6
// baseline (288.784 us; speedup 1.0000x reference)
//
#include <hip/hip_runtime.h>

#define BB 256
#define NP 12
#define TT 20
#define DD 512
#define EPS_A 1e-6f
#define EPS_BN 1e-5f
#define THR2 (150.0f * 150.0f)
#define APITCH 520            // ushorts per A-tile row (1040 B)
#define CTOTAL 7864320L       // pf/out size in float4 units
#define NCPY 2048             // dense-copy blocks: 2048*256 threads * 15 iters = CTOTAL exactly

typedef __attribute__((ext_vector_type(8))) short shortx8;
typedef __attribute__((ext_vector_type(4))) float floatx4;

static __device__ __forceinline__ ushort f2bf(float f) {
    unsigned x = __float_as_uint(f);
    return (ushort)((x + 0x7fffu + ((x >> 16) & 1u)) >> 16);  // RNE
}

// ---------------------------------------------------------------------------
// K_A: [0,64) cast W1,W2 -> bf16 ; [64] BN vecs ; [65,65+NCPY) DENSE copy.
// Copy is the exact m13 µbench pattern: lane i -> float4 i, grid-stride,
// zero LDS, zero branches, no skip (slice rows overwritten by K_B later).
// 15 iterations exactly, unroll 3 (3 loads in flight per lane).
// ---------------------------------------------------------------------------
__global__ __launch_bounds__(256) void k_copyA(
    const float* __restrict__ W1, const float* __restrict__ W2,
    const float* __restrict__ b1, const float* __restrict__ g1,
    const float* __restrict__ beta1, const float* __restrict__ m1, const float* __restrict__ v1,
    const float* __restrict__ b2, const float* __restrict__ g2,
    const float* __restrict__ beta2, const float* __restrict__ m2, const float* __restrict__ v2,
    float* __restrict__ s1, float* __restrict__ t1, float* __restrict__ s2, float* __restrict__ t2,
    ushort* __restrict__ wb1, ushort* __restrict__ wb2,
    const float4* __restrict__ csrc, float4* __restrict__ cdst) {
    int bid = blockIdx.x, t = threadIdx.x;
    if (bid >= 65) {
        const long stride = (long)NCPY * 256;        // 524288
        long g = (long)(bid - 65) * 256 + t;         // < stride
        #pragma unroll
        for (int it = 0; it < 5; it++) {             // 5 * 3 = 15 sweeps, exact cover
            float4 a = csrc[g];
            float4 b = csrc[g + stride];
            float4 c = csrc[g + 2 * stride];
            cdst[g] = a;
            cdst[g + stride] = b;
            cdst[g + 2 * stride] = c;
            g += 3 * stride;
        }
    } else if (bid < 64) {  // 131072 float4 total (W1 then W2), 8 iters
        int idx = bid * 256 + t;
        #pragma unroll
        for (int k = 0; k < 8; k++) {
            int i = idx + k * 16384;
            float4 f = (i < 65536) ? ((const float4*)W1)[i] : ((const float4*)W2)[i - 65536];
            ushort4 u;
            u.x = f2bf(f.x); u.y = f2bf(f.y); u.z = f2bf(f.z); u.w = f2bf(f.w);
            if (i < 65536) *(ushort4*)(wb1 + (long)i * 4) = u;
            else           *(ushort4*)(wb2 + (long)(i - 65536) * 4) = u;
        }
    } else {  // bid == 64
        for (int d = t; d < DD; d += 256) {
            float sa = g1[d] * rsqrtf(v1[d] + EPS_BN);
            s1[d] = sa; t1[d] = (b1[d] - m1[d]) * sa + beta1[d];
            float sb = g2[d] * rsqrtf(v2[d] + EPS_BN);
            s2[d] = sb; t2[d] = (b2[d] - m2[d]) * sb + beta2[d];
        }
    }
}

// ---------------------------------------------------------------------------
// Per-batch GEMM, 8 waves: wave owns 64 output cols (4 n-tiles). M=12 in one
// 16-row tile. A from LDS, B (bf16 W) streamed from global (L2/L3-hot).
// ---------------------------------------------------------------------------
template <int LAYER>
static __device__ __forceinline__ void gemm8w(
    int wave, int lane, int b,
    const ushort (*__restrict__ xgl)[APITCH], float (*__restrict__ y1l)[DD],
    const ushort* __restrict__ wb, const float* __restrict__ sv, const float* __restrict__ tv,
    float* __restrict__ outp) {
    int mrow = lane & 15, quad = lane >> 4;
    floatx4 acc[4];
    #pragma unroll
    for (int nt = 0; nt < 4; nt++) acc[nt] = (floatx4){0.f, 0.f, 0.f, 0.f};

    const ushort* wbase = wb + ((long)(wave * 64 + mrow)) * DD + quad * 8;
    #pragma unroll 4
    for (int kc = 0; kc < DD; kc += 32) {
        shortx8 af = *(const shortx8*)&xgl[mrow][kc + quad * 8];
        #pragma unroll
        for (int nt = 0; nt < 4; nt++) {
            shortx8 bf = *(const shortx8*)(wbase + nt * 16 * DD + kc);
            acc[nt] = __builtin_amdgcn_mfma_f32_16x16x32_bf16(af, bf, acc[nt], 0, 0, 0);
        }
    }

    #pragma unroll
    for (int nt = 0; nt < 4; nt++) {
        int d = wave * 64 + nt * 16 + mrow;
        float s = sv[d], tt = tv[d];
        #pragma unroll
        for (int v = 0; v < 4; v++) {
            int m = quad * 4 + v;
            float val = fmaxf(acc[nt][v] * s + tt, 0.f);
            if (m < NP) {
                if (LAYER == 1) y1l[m][d] = val;
                else outp[((long)(b * NP + m) * TT + (TT - 1)) * DD + d] = val;
            }
        }
    }
}

// ---------------------------------------------------------------------------
// K_B: 256 blocks, full per-batch STGCN chain; overwrites the t==19 rows of
// out (which K_A filled with stale copies). Runs after K_A on the stream.
// ---------------------------------------------------------------------------
__global__ __launch_bounds__(512, 4) void k_compute(
    const float* __restrict__ pf, const float* __restrict__ bboxes,
    const ushort* __restrict__ wb1, const ushort* __restrict__ wb2,
    const float* __restrict__ s1, const float* __restrict__ t1,
    const float* __restrict__ s2, const float* __restrict__ t2,
    float* __restrict__ out) {
    __shared__ float cx[NP], cy[NP], Ash[NP][NP], rinv[NP], at[NP][NP];
    __shared__ __align__(16) ushort xgl[16][APITCH];  // bf16 A-tile (rows 12..15 zero)
    __shared__ float y1l[NP][DD];                     // fp32 layer-1 output

    int b = blockIdx.x, t = threadIdx.x;
    int lane = t & 63, wave = t >> 6;

    // ---- adjacency ----
    if (t < NP) {
        const float* p = bboxes + (b * NP + t) * 4;
        cx[t] = p[0] + 0.5f * p[2];
        cy[t] = p[1] + 0.5f * p[3];
    }
    // zero pad rows 12..15 of xgl (MFMA reads them; must be 0)
    {
        uint* xz = (uint*)&xgl[NP][0];
        for (int i = t; i < 4 * APITCH / 2; i += 512) xz[i] = 0;
    }
    __syncthreads();
    if (t < NP * NP) {
        int n = t / NP, k = t % NP;
        float dx = cx[n] - cx[k], dy = cy[n] - cy[k];
        Ash[n][k] = (dx * dx + dy * dy < THR2) ? 1.f : 0.f;
    }
    __syncthreads();
    if (t < NP) {
        float s = 0.f;
        #pragma unroll
        for (int k = 0; k < NP; k++) s += Ash[t][k];
        rinv[t] = 1.f / (s + EPS_A);
    }
    __syncthreads();
    if (t < NP * NP) {
        int j = t / NP, n = t % NP;
        at[j][n] = Ash[n][j] * rinv[n];
    }
    __syncthreads();

    // ---- mix1: pf last slice -> xgl (bf16) ----
    for (int c = t; c < DD; c += 512) {
        float xv[NP];
        #pragma unroll
        for (int n = 0; n < NP; n++)
            xv[n] = pf[((long)((b * NP + n) * TT + TT - 1)) * DD + c];
        #pragma unroll
        for (int j = 0; j < NP; j++) {
            float a = 0.f;
            #pragma unroll
            for (int n = 0; n < NP; n++) a += at[j][n] * xv[n];
            xgl[j][c] = f2bf(a);
        }
    }
    __syncthreads();

    // ---- layer 1 GEMM + BN + relu -> y1l ----
    gemm8w<1>(wave, lane, b, xgl, y1l, wb1, s1, t1, nullptr);
    __syncthreads();  // y1l written; xgl reads done

    // ---- mix2: y1l -> xgl (bf16) ----
    for (int c = t; c < DD; c += 512) {
        float xv[NP];
        #pragma unroll
        for (int n = 0; n < NP; n++) xv[n] = y1l[n][c];
        #pragma unroll
        for (int j = 0; j < NP; j++) {
            float a = 0.f;
            #pragma unroll
            for (int n = 0; n < NP; n++) a += at[j][n] * xv[n];
            xgl[j][c] = f2bf(a);
        }
    }
    __syncthreads();

    // ---- layer 2 GEMM + BN + relu -> out slice rows (overwrite stale copy) ----
    gemm8w<2>(wave, lane, b, xgl, y1l, wb2, s2, t2, out);
}

// ---------------------------------------------------------------------------
extern "C" void kernel_launch(void* const* d_in, const int* in_sizes, int n_in,
                              void* d_out, int out_size, void* d_ws, size_t ws_size,
                              hipStream_t stream) {
    const float* pf = (const float*)d_in[0];
    const float* bboxes = (const float*)d_in[1];
    const float* W1 = (const float*)d_in[2];
    const float* b1 = (const float*)d_in[3];
    const float* g1 = (const float*)d_in[4];
    const float* beta1 = (const float*)d_in[5];
    const float* m1 = (const float*)d_in[6];
    const float* v1 = (const float*)d_in[7];
    const float* W2 = (const float*)d_in[8];
    const float* b2 = (const float*)d_in[9];
    const float* g2 = (const float*)d_in[10];
    const float* beta2 = (const float*)d_in[11];
    const float* m2 = (const float*)d_in[12];
    const float* v2 = (const float*)d_in[13];
    float* out = (float*)d_out;

    float* ws = (float*)d_ws;
    float* s1 = ws;
    float* t1v = ws + 512;
    float* s2 = ws + 1024;
    float* t2v = ws + 1536;
    ushort* wb1 = (ushort*)(ws + 2048);   // 262144 ushorts
    ushort* wb2 = wb1 + 262144;           // 262144 ushorts

    const float4* csrc = (const float4*)pf;
    float4* cdst = (float4*)out;

    k_copyA<<<65 + NCPY, 256, 0, stream>>>(W1, W2, b1, g1, beta1, m1, v1,
                                           b2, g2, beta2, m2, v2,
                                           s1, t1v, s2, t2v, wb1, wb2, csrc, cdst);
    k_compute<<<BB, 512, 0, stream>>>(pf, bboxes, wb1, wb2,
                                      s1, t1v, s2, t2v, out);
}

// Round 7
// 284.387 us; speedup vs baseline: 1.0155x; 1.0155x over previous
//
#include <hip/hip_runtime.h>

#define BB 256
#define NP 12
#define TT 20
#define DD 512
#define EPS_A 1e-6f
#define EPS_BN 1e-5f
#define THR2 (150.0f * 150.0f)
#define APITCH 520            // ushorts per A-tile row (1040 B)
#define CTOTAL 7864320L       // pf/out size in float4 units
#define NCPY 2048             // copy blocks: 2048 * 3840 f4/block = CTOTAL exactly

typedef __attribute__((ext_vector_type(8))) short shortx8;
typedef __attribute__((ext_vector_type(4))) float floatx4;

static __device__ __forceinline__ ushort f2bf(float f) {
    unsigned x = __float_as_uint(f);
    return (ushort)((x + 0x7fffu + ((x >> 16) & 1u)) >> 16);  // RNE
}

// ---------------------------------------------------------------------------
// K_A: [0,64) cast W1,W2 -> bf16 ; [64] BN vecs ; [65,65+NCPY) DENSE copy.
// Copy: block owns a CONTIGUOUS 3840-float4 chunk. Each thread loads its 15
// float4 into registers (15-deep pure READ burst, no store interleaved),
// then stores all 15. Phase-separates reads from writes so vmcnt waits for
// stores never gate outstanding loads (vmcnt is a shared in-order counter).
// Slice rows copied stale; K_B overwrites them.
// ---------------------------------------------------------------------------
__global__ __launch_bounds__(256) void k_copyA(
    const float* __restrict__ W1, const float* __restrict__ W2,
    const float* __restrict__ b1, const float* __restrict__ g1,
    const float* __restrict__ beta1, const float* __restrict__ m1, const float* __restrict__ v1,
    const float* __restrict__ b2, const float* __restrict__ g2,
    const float* __restrict__ beta2, const float* __restrict__ m2, const float* __restrict__ v2,
    float* __restrict__ s1, float* __restrict__ t1, float* __restrict__ s2, float* __restrict__ t2,
    ushort* __restrict__ wb1, ushort* __restrict__ wb2,
    const float4* __restrict__ csrc, float4* __restrict__ cdst) {
    int bid = blockIdx.x, t = threadIdx.x;
    if (bid >= 65) {
        long g0 = (long)(bid - 65) * 3840 + t;  // block chunk: 3840 consecutive f4
        float4 v[15];
        #pragma unroll
        for (int k = 0; k < 15; k++) v[k] = csrc[g0 + k * 256];
        #pragma unroll
        for (int k = 0; k < 15; k++) cdst[g0 + k * 256] = v[k];
    } else if (bid < 64) {  // 131072 float4 total (W1 then W2), 8 iters
        int idx = bid * 256 + t;
        #pragma unroll
        for (int k = 0; k < 8; k++) {
            int i = idx + k * 16384;
            float4 f = (i < 65536) ? ((const float4*)W1)[i] : ((const float4*)W2)[i - 65536];
            ushort4 u;
            u.x = f2bf(f.x); u.y = f2bf(f.y); u.z = f2bf(f.z); u.w = f2bf(f.w);
            if (i < 65536) *(ushort4*)(wb1 + (long)i * 4) = u;
            else           *(ushort4*)(wb2 + (long)(i - 65536) * 4) = u;
        }
    } else {  // bid == 64
        for (int d = t; d < DD; d += 256) {
            float sa = g1[d] * rsqrtf(v1[d] + EPS_BN);
            s1[d] = sa; t1[d] = (b1[d] - m1[d]) * sa + beta1[d];
            float sb = g2[d] * rsqrtf(v2[d] + EPS_BN);
            s2[d] = sb; t2[d] = (b2[d] - m2[d]) * sb + beta2[d];
        }
    }
}

// ---------------------------------------------------------------------------
// Per-batch GEMM, 8 waves: wave owns 64 output cols (4 n-tiles). M=12 in one
// 16-row tile. A from LDS, B (bf16 W) streamed from global (L2/L3-hot).
// ---------------------------------------------------------------------------
template <int LAYER>
static __device__ __forceinline__ void gemm8w(
    int wave, int lane, int b,
    const ushort (*__restrict__ xgl)[APITCH], float (*__restrict__ y1l)[DD],
    const ushort* __restrict__ wb, const float* __restrict__ sv, const float* __restrict__ tv,
    float* __restrict__ outp) {
    int mrow = lane & 15, quad = lane >> 4;
    floatx4 acc[4];
    #pragma unroll
    for (int nt = 0; nt < 4; nt++) acc[nt] = (floatx4){0.f, 0.f, 0.f, 0.f};

    const ushort* wbase = wb + ((long)(wave * 64 + mrow)) * DD + quad * 8;
    #pragma unroll 4
    for (int kc = 0; kc < DD; kc += 32) {
        shortx8 af = *(const shortx8*)&xgl[mrow][kc + quad * 8];
        #pragma unroll
        for (int nt = 0; nt < 4; nt++) {
            shortx8 bf = *(const shortx8*)(wbase + nt * 16 * DD + kc);
            acc[nt] = __builtin_amdgcn_mfma_f32_16x16x32_bf16(af, bf, acc[nt], 0, 0, 0);
        }
    }

    #pragma unroll
    for (int nt = 0; nt < 4; nt++) {
        int d = wave * 64 + nt * 16 + mrow;
        float s = sv[d], tt = tv[d];
        #pragma unroll
        for (int v = 0; v < 4; v++) {
            int m = quad * 4 + v;
            float val = fmaxf(acc[nt][v] * s + tt, 0.f);
            if (m < NP) {
                if (LAYER == 1) y1l[m][d] = val;
                else outp[((long)(b * NP + m) * TT + (TT - 1)) * DD + d] = val;
            }
        }
    }
}

// ---------------------------------------------------------------------------
// K_B: 256 blocks, full per-batch STGCN chain; overwrites the t==19 rows of
// out (which K_A filled with stale copies). Runs after K_A on the stream.
// ---------------------------------------------------------------------------
__global__ __launch_bounds__(512, 4) void k_compute(
    const float* __restrict__ pf, const float* __restrict__ bboxes,
    const ushort* __restrict__ wb1, const ushort* __restrict__ wb2,
    const float* __restrict__ s1, const float* __restrict__ t1,
    const float* __restrict__ s2, const float* __restrict__ t2,
    float* __restrict__ out) {
    __shared__ float cx[NP], cy[NP], Ash[NP][NP], rinv[NP], at[NP][NP];
    __shared__ __align__(16) ushort xgl[16][APITCH];  // bf16 A-tile (rows 12..15 zero)
    __shared__ float y1l[NP][DD];                     // fp32 layer-1 output

    int b = blockIdx.x, t = threadIdx.x;
    int lane = t & 63, wave = t >> 6;

    // ---- adjacency ----
    if (t < NP) {
        const float* p = bboxes + (b * NP + t) * 4;
        cx[t] = p[0] + 0.5f * p[2];
        cy[t] = p[1] + 0.5f * p[3];
    }
    // zero pad rows 12..15 of xgl (MFMA reads them; must be 0)
    {
        uint* xz = (uint*)&xgl[NP][0];
        for (int i = t; i < 4 * APITCH / 2; i += 512) xz[i] = 0;
    }
    __syncthreads();
    if (t < NP * NP) {
        int n = t / NP, k = t % NP;
        float dx = cx[n] - cx[k], dy = cy[n] - cy[k];
        Ash[n][k] = (dx * dx + dy * dy < THR2) ? 1.f : 0.f;
    }
    __syncthreads();
    if (t < NP) {
        float s = 0.f;
        #pragma unroll
        for (int k = 0; k < NP; k++) s += Ash[t][k];
        rinv[t] = 1.f / (s + EPS_A);
    }
    __syncthreads();
    if (t < NP * NP) {
        int j = t / NP, n = t % NP;
        at[j][n] = Ash[n][j] * rinv[n];
    }
    __syncthreads();

    // ---- mix1: pf last slice -> xgl (bf16) ----
    for (int c = t; c < DD; c += 512) {
        float xv[NP];
        #pragma unroll
        for (int n = 0; n < NP; n++)
            xv[n] = pf[((long)((b * NP + n) * TT + TT - 1)) * DD + c];
        #pragma unroll
        for (int j = 0; j < NP; j++) {
            float a = 0.f;
            #pragma unroll
            for (int n = 0; n < NP; n++) a += at[j][n] * xv[n];
            xgl[j][c] = f2bf(a);
        }
    }
    __syncthreads();

    // ---- layer 1 GEMM + BN + relu -> y1l ----
    gemm8w<1>(wave, lane, b, xgl, y1l, wb1, s1, t1, nullptr);
    __syncthreads();  // y1l written; xgl reads done

    // ---- mix2: y1l -> xgl (bf16) ----
    for (int c = t; c < DD; c += 512) {
        float xv[NP];
        #pragma unroll
        for (int n = 0; n < NP; n++) xv[n] = y1l[n][c];
        #pragma unroll
        for (int j = 0; j < NP; j++) {
            float a = 0.f;
            #pragma unroll
            for (int n = 0; n < NP; n++) a += at[j][n] * xv[n];
            xgl[j][c] = f2bf(a);
        }
    }
    __syncthreads();

    // ---- layer 2 GEMM + BN + relu -> out slice rows (overwrite stale copy) ----
    gemm8w<2>(wave, lane, b, xgl, y1l, wb2, s2, t2, out);
}

// ---------------------------------------------------------------------------
extern "C" void kernel_launch(void* const* d_in, const int* in_sizes, int n_in,
                              void* d_out, int out_size, void* d_ws, size_t ws_size,
                              hipStream_t stream) {
    const float* pf = (const float*)d_in[0];
    const float* bboxes = (const float*)d_in[1];
    const float* W1 = (const float*)d_in[2];
    const float* b1 = (const float*)d_in[3];
    const float* g1 = (const float*)d_in[4];
    const float* beta1 = (const float*)d_in[5];
    const float* m1 = (const float*)d_in[6];
    const float* v1 = (const float*)d_in[7];
    const float* W2 = (const float*)d_in[8];
    const float* b2 = (const float*)d_in[9];
    const float* g2 = (const float*)d_in[10];
    const float* beta2 = (const float*)d_in[11];
    const float* m2 = (const float*)d_in[12];
    const float* v2 = (const float*)d_in[13];
    float* out = (float*)d_out;

    float* ws = (float*)d_ws;
    float* s1 = ws;
    float* t1v = ws + 512;
    float* s2 = ws + 1024;
    float* t2v = ws + 1536;
    ushort* wb1 = (ushort*)(ws + 2048);   // 262144 ushorts
    ushort* wb2 = wb1 + 262144;           // 262144 ushorts

    const float4* csrc = (const float4*)pf;
    float4* cdst = (float4*)out;

    k_copyA<<<65 + NCPY, 256, 0, stream>>>(W1, W2, b1, g1, beta1, m1, v1,
                                           b2, g2, beta2, m2, v2,
                                           s1, t1v, s2, t2v, wb1, wb2, csrc, cdst);
    k_compute<<<BB, 512, 0, stream>>>(pf, bboxes, wb1, wb2,
                                      s1, t1v, s2, t2v, out);
}